// Round 1
// 756.354 us; speedup vs baseline: 1.0192x; 1.0192x over previous
//
#include <hip/hip_runtime.h>
#include <math.h>

typedef __attribute__((ext_vector_type(8))) short bf16x8;
typedef __attribute__((ext_vector_type(4))) float f32x4;

#define NN 131072

// ---- d_out offsets (float elements), reference tuple order ----
#define COST_OFF   ((size_t)0)
#define CEXT_OFF   ((size_t)33554432)
#define CEXT_DUST  ((size_t)67108864)   // cost_ext row 256
#define MD_OFF     ((size_t)67239936)   // min_distance
#define PLAN_OFF   ((size_t)67371008)
#define LOSS_OFF   ((size_t)101056512)
#define DUSTC_OFF  ((size_t)101056513)
#define RATIO_OFF  ((size_t)101056514)
#define DUS_OFF    ((size_t)101056515)  // distance_unknown_score
#define CS_OFF     ((size_t)101187587)  // class_scores
#define DSC_OFF    ((size_t)134742019)  // dustbin_scores
#define BKM_OFF    ((size_t)134873091)  // best_known_mass
#define MUNK_OFF   ((size_t)135004163)  // mass_unknown_score
#define ASSIGN_OFF ((size_t)135135235)  // assignment (as float)

// ---- d_ws offsets (32-bit words) ----
#define WS_X2     0      // 256 f32
#define WS_Q      256
#define WS_DSC    257
#define WS_BKM    258
#define WS_MUNK   259
#define WS_AVAL   260
#define WS_PROW   264    // 257 f32
#define WS_CS     524    // 256 f32
#define WS_SPCNT  780
#define WS_SPDATA 784    // 3*SPCAP
#define SPCAP     1024
// frag-direct A layout: [ck][row][qd][8] bf16 = 8*256*4*8 u16 = 65536 u16 = 32768 words/plane
#define WS_AH     4096
#define WS_AL     36864
#define WS_RS     86016  // 32 copies x 256 f32 = 8192 words
#define WS_HC     94208  // 32 copies x 2048 u32 = 65536 words
#define NCOPY     32

#define HBINS  2048
#define HSCALE 32.0f     // bins over [0,64), width 1/32

__device__ __forceinline__ unsigned short f2bf(float x) {
    unsigned u = __float_as_uint(x);
    return (unsigned short)((u + 0x7fffu + ((u >> 16) & 1u)) >> 16);
}
__device__ __forceinline__ float bf2f(unsigned short h) {
    return __uint_as_float(((unsigned)h) << 16);
}

// ---------------- K0: init — A frag-layout split precompute, x2 norms, zero accumulators ----
__global__ __launch_bounds__(256) void k_init(const float* __restrict__ A,
                                              float* __restrict__ wsf,
                                              unsigned* __restrict__ wsu)
{
    __shared__ float red[4];
    const int b = blockIdx.x, t = threadIdx.x;
    if (b < 256) {
        float a = A[b * 256 + t];
        unsigned short h = f2bf(a);
        unsigned short l = f2bf(a - bf2f(h));
        int ck = t >> 5;
        unsigned short* AH = (unsigned short*)(wsu + WS_AH);
        unsigned short* AL = (unsigned short*)(wsu + WS_AL);
        // frag-direct: off = ((ck*256 + row)*4 + qd)*8 + j == ck*8192 + row*32 + (t&31)
        int off = ck * 8192 + b * 32 + (t & 31);
        AH[off] = h;
        AL[off] = l;
        float s = a * a;
        s += __shfl_xor(s, 1);  s += __shfl_xor(s, 2);  s += __shfl_xor(s, 4);
        s += __shfl_xor(s, 8);  s += __shfl_xor(s, 16); s += __shfl_xor(s, 32);
        if ((t & 63) == 0) red[t >> 6] = s;
        __syncthreads();
        if (t == 0) wsf[WS_X2 + b] = red[0] + red[1] + red[2] + red[3];
    } else {
        int zb = b - 256;  // 64 zero blocks
        for (int i = zb * 256 + t; i < NCOPY * HBINS; i += 64 * 256) wsu[WS_HC + i] = 0u;
        for (int i = zb * 256 + t; i < NCOPY * 256; i += 64 * 256) wsu[WS_RS + i] = 0u;
        if (zb == 0 && t == 0) wsu[WS_SPCNT] = 0u;
    }
}

// ---------------- K1: cost GEMM (split-bf16 MFMA) + fused epilogue ----------------
// Pipeline: A frags direct from L2 (reg double-buffered, prefetched 1 chunk ahead);
// B LDS double-buffered with depth-2 HBM prefetch; ONE barrier per K-chunk.
__global__ __launch_bounds__(256, 2) void k_cost(const float* __restrict__ B,
                                                 float* __restrict__ out,
                                                 unsigned* __restrict__ wsu,
                                                 float* __restrict__ wsf)
{
    __shared__ alignas(16) unsigned short Bh[2][64 * 40];
    __shared__ alignas(16) unsigned short Bl[2][64 * 40];
    __shared__ unsigned histL[HBINS];
    __shared__ float x2s[256];
    __shared__ float y2s[64];
    __shared__ unsigned cminL[64];

    const int t = threadIdx.x;
    const int w = t >> 6;
    const int lane = t & 63;
    const int qd = lane >> 4;
    const int cl = lane & 15;
    const int j0 = blockIdx.x * 64;
    const int cpy = blockIdx.x & (NCOPY - 1);

    const unsigned short* AH_g = (const unsigned short*)(wsu + WS_AH);
    const unsigned short* AL_g = (const unsigned short*)(wsu + WS_AL);

    x2s[t] = wsf[WS_X2 + t];
    if (t < 64) cminL[t] = 0x7f800000u;
    for (int b = t; b < HBINS; b += 256) histL[b] = 0u;

    f32x4 acc[4][4];
#pragma unroll
    for (int fm = 0; fm < 4; ++fm)
#pragma unroll
        for (int fn = 0; fn < 4; ++fn) acc[fm][fn] = (f32x4){0.f, 0.f, 0.f, 0.f};

    float y2p0 = 0.f, y2p1 = 0.f;

    // B staging geometry (same as verified kernel: flat = it*256 + t)
    const int rB0 = t >> 3,         cB0 = (t & 7) * 4;
    const int rB1 = (256 + t) >> 3, cB1 = ((256 + t) & 7) * 4;
    const size_t bbase0 = (size_t)(j0 + rB0) * 256 + (size_t)cB0;
    const size_t bbase1 = (size_t)(j0 + rB1) * 256 + (size_t)cB1;
    const int wboff0 = rB0 * 40 + cB0;
    const int wboff1 = rB1 * 40 + cB1;

    // prologue: B f32 for chunks 0 and 1 in flight
    float4 vb[2][2];
    vb[0][0] = *(const float4*)(B + bbase0);
    vb[0][1] = *(const float4*)(B + bbase1);
    vb[1][0] = *(const float4*)(B + bbase0 + 32);
    vb[1][1] = *(const float4*)(B + bbase1 + 32);

    // prologue: A frags for chunk 0 in flight (16B/lane, fully coalesced, L2-resident)
    const int arow_base = w * 64 + cl;
    bf16x8 cah[2][4], cal[2][4];
#pragma unroll
    for (int fm = 0; fm < 4; ++fm) {
        int off = ((arow_base + fm * 16) * 4 + qd) * 8;
        cah[0][fm] = *(const bf16x8*)(AH_g + off);
        cal[0][fm] = *(const bf16x8*)(AL_g + off);
    }

#define CHUNK_BODY(CK, P, PN)                                                         \
    {                                                                                 \
        {   /* convert staged B f32 regs (chunk CK) -> LDS buffer P */                \
            float4 v = vb[P][0];                                                      \
            y2p0 += v.x * v.x + v.y * v.y + v.z * v.z + v.w * v.w;                    \
            unsigned short h0 = f2bf(v.x), h1 = f2bf(v.y), h2 = f2bf(v.z), h3 = f2bf(v.w); \
            unsigned short g0 = f2bf(v.x - bf2f(h0)), g1 = f2bf(v.y - bf2f(h1));      \
            unsigned short g2 = f2bf(v.z - bf2f(h2)), g3 = f2bf(v.w - bf2f(h3));      \
            *(uint2*)(&Bh[P][wboff0]) = make_uint2((unsigned)h0 | ((unsigned)h1 << 16), \
                                                   (unsigned)h2 | ((unsigned)h3 << 16)); \
            *(uint2*)(&Bl[P][wboff0]) = make_uint2((unsigned)g0 | ((unsigned)g1 << 16), \
                                                   (unsigned)g2 | ((unsigned)g3 << 16)); \
        }                                                                             \
        {                                                                             \
            float4 v = vb[P][1];                                                      \
            y2p1 += v.x * v.x + v.y * v.y + v.z * v.z + v.w * v.w;                    \
            unsigned short h0 = f2bf(v.x), h1 = f2bf(v.y), h2 = f2bf(v.z), h3 = f2bf(v.w); \
            unsigned short g0 = f2bf(v.x - bf2f(h0)), g1 = f2bf(v.y - bf2f(h1));      \
            unsigned short g2 = f2bf(v.z - bf2f(h2)), g3 = f2bf(v.w - bf2f(h3));      \
            *(uint2*)(&Bh[P][wboff1]) = make_uint2((unsigned)h0 | ((unsigned)h1 << 16), \
                                                   (unsigned)h2 | ((unsigned)h3 << 16)); \
            *(uint2*)(&Bl[P][wboff1]) = make_uint2((unsigned)g0 | ((unsigned)g1 << 16), \
                                                   (unsigned)g2 | ((unsigned)g3 << 16)); \
        }                                                                             \
        if ((CK) < 6) { /* depth-2 HBM prefetch: B f32 for chunk CK+2 */              \
            vb[P][0] = *(const float4*)(B + bbase0 + ((CK) + 2) * 32);                \
            vb[P][1] = *(const float4*)(B + bbase1 + ((CK) + 2) * 32);                \
        }                                                                             \
        __syncthreads();                                                              \
        if ((CK) < 7) { /* prefetch A frags for chunk CK+1 (hidden under MFMAs) */    \
            _Pragma("unroll")                                                         \
            for (int fm = 0; fm < 4; ++fm) {                                          \
                int off = ((((CK) + 1) * 256 + arow_base + fm * 16) * 4 + qd) * 8;    \
                cah[PN][fm] = *(const bf16x8*)(AH_g + off);                           \
                cal[PN][fm] = *(const bf16x8*)(AL_g + off);                           \
            }                                                                         \
        }                                                                             \
        {                                                                             \
            bf16x8 bh[4], bl[4];                                                      \
            _Pragma("unroll")                                                         \
            for (int fn = 0; fn < 4; ++fn) {                                          \
                int off = (fn * 16 + cl) * 40 + qd * 8;                               \
                bh[fn] = *(const bf16x8*)(&Bh[P][off]);                               \
                bl[fn] = *(const bf16x8*)(&Bl[P][off]);                               \
            }                                                                         \
            _Pragma("unroll")                                                         \
            for (int fm = 0; fm < 4; ++fm)                                            \
            _Pragma("unroll")                                                         \
                for (int fn = 0; fn < 4; ++fn) {                                      \
                    f32x4 a = acc[fm][fn];                                            \
                    a = __builtin_amdgcn_mfma_f32_16x16x32_bf16(cah[P][fm], bh[fn], a, 0, 0, 0); \
                    a = __builtin_amdgcn_mfma_f32_16x16x32_bf16(cah[P][fm], bl[fn], a, 0, 0, 0); \
                    a = __builtin_amdgcn_mfma_f32_16x16x32_bf16(cal[P][fm], bh[fn], a, 0, 0, 0); \
                    acc[fm][fn] = a;                                                  \
                }                                                                     \
        }                                                                             \
    }

    CHUNK_BODY(0, 0, 1)
    CHUNK_BODY(1, 1, 0)
    CHUNK_BODY(2, 0, 1)
    CHUNK_BODY(3, 1, 0)
    CHUNK_BODY(4, 0, 1)
    CHUNK_BODY(5, 1, 0)
    CHUNK_BODY(6, 0, 1)
    CHUNK_BODY(7, 1, 0)
#undef CHUNK_BODY

    // y2 reduce: 8 lanes share one target row
    {
        float v = y2p0;
        v += __shfl_xor(v, 1); v += __shfl_xor(v, 2); v += __shfl_xor(v, 4);
        if ((t & 7) == 0) y2s[t >> 3] = v;
        v = y2p1;
        v += __shfl_xor(v, 1); v += __shfl_xor(v, 2); v += __shfl_xor(v, 4);
        if ((t & 7) == 0) y2s[32 + (t >> 3)] = v;
    }
    __syncthreads();

    // ---- epilogue ----
    float x2v[16];
#pragma unroll
    for (int fm = 0; fm < 4; ++fm)
#pragma unroll
        for (int r = 0; r < 4; ++r)
            x2v[fm * 4 + r] = x2s[w * 64 + fm * 16 + qd * 4 + r];
    float y2v[4];
#pragma unroll
    for (int fn = 0; fn < 4; ++fn) y2v[fn] = y2s[fn * 16 + cl];

    float rp[16];
#pragma unroll
    for (int i = 0; i < 16; ++i) rp[i] = 0.f;
    float cmv[4] = {1e30f, 1e30f, 1e30f, 1e30f};

#pragma unroll
    for (int fm = 0; fm < 4; ++fm)
#pragma unroll
        for (int fn = 0; fn < 4; ++fn) {
#pragma unroll
            for (int r = 0; r < 4; ++r) {
                float d2 = x2v[fm * 4 + r] + y2v[fn] - 2.0f * acc[fm][fn][r];
                float cst = sqrtf(fmaxf(d2, 0.0f));
                int row = w * 64 + fm * 16 + qd * 4 + r;
                int col = j0 + fn * 16 + cl;
                size_t idx = (size_t)row * NN + (size_t)col;
                out[idx] = cst;
                out[CEXT_OFF + idx] = cst;
                int bin = (int)(cst * HSCALE);
                bin = bin < (HBINS - 1) ? bin : (HBINS - 1);
                atomicAdd(&histL[bin], 1u);
                rp[fm * 4 + r] += cst;
                cmv[fn] = fminf(cmv[fn], cst);
                if (cst < 0.92103404f) {   // exp(-c/eps) > 1e-8 only below this
                    unsigned id = atomicAdd(&wsu[WS_SPCNT], 1u);
                    if (id < SPCAP) {
                        wsu[WS_SPDATA + 3 * id]     = (unsigned)row;
                        wsu[WS_SPDATA + 3 * id + 1] = (unsigned)col;
                        wsf[WS_SPDATA + 3 * id + 2] = cst;
                    }
                }
            }
        }
    // column minima (block covers ALL rows -> plain store later, no global atomic)
#pragma unroll
    for (int fn = 0; fn < 4; ++fn) {
        float v = cmv[fn];
        v = fminf(v, __shfl_xor(v, 16));
        v = fminf(v, __shfl_xor(v, 32));
        if (qd == 0) atomicMin(&cminL[fn * 16 + cl], __float_as_uint(v));
    }
    // row sums -> striped copy (32x less same-address contention)
#pragma unroll
    for (int i = 0; i < 16; ++i) {
        float v = rp[i];
        v += __shfl_xor(v, 1); v += __shfl_xor(v, 2); v += __shfl_xor(v, 4); v += __shfl_xor(v, 8);
        if (cl == 0) atomicAdd(&wsf[WS_RS + cpy * 256 + w * 64 + (i >> 2) * 16 + qd * 4 + (i & 3)], v);
    }
    __syncthreads();
    for (int b = t; b < HBINS; b += 256) {
        unsigned h = histL[b];
        if (h) atomicAdd(&wsu[WS_HC + cpy * HBINS + b], h);
    }
    if (t < 64) ((unsigned*)out)[MD_OFF + j0 + t] = cminL[t];
}

// ---------------- K2: reduce striped accumulators + quantile + scalar Sinkhorn ------
__global__ __launch_bounds__(256) void k_solve(unsigned* __restrict__ wsu,
                                               float* __restrict__ wsf,
                                               float* __restrict__ out)
{
    __shared__ unsigned hh[HBINS];
    __shared__ unsigned psum[256];
    __shared__ double sh_u[257];
    __shared__ double shb[8];
    __shared__ double shred[4];
    __shared__ float csf[256];
    __shared__ int sp_r[SPCAP];
    __shared__ float sp_k[SPCAP];
    __shared__ int colof[SPCAP];
    __shared__ int colid[SPCAP];
    __shared__ double vov[SPCAP];
    __shared__ int sh_ni[2];

    const int t = threadIdx.x;
    const int wid = t >> 6;

    // reduce histogram copies
    unsigned p = 0;
#pragma unroll
    for (int i = 0; i < HBINS / 256; ++i) {
        int b = t * (HBINS / 256) + i;
        unsigned s = 0;
        for (int c = 0; c < NCOPY; ++c) s += wsu[WS_HC + c * HBINS + b];
        hh[b] = s;
        p += s;
    }
    psum[t] = p;
    // reduce rowsum copies
    float rs_t = 0.f;
    for (int c = 0; c < NCOPY; ++c) rs_t += wsf[WS_RS + c * 256 + t];
    __syncthreads();

    if (t == 0) {
        double idxf = 0.8 * (double)(33554432 - 1);
        long long r0 = (long long)idxf;
        double frac = idxf - (double)r0;
        double vq[2];
        for (int s = 0; s < 2; ++s) {
            long long target = r0 + s;
            long long cum = 0;
            int ch = 0;
            while (ch < 255 && cum + (long long)psum[ch] <= target) { cum += psum[ch]; ++ch; }
            int b = ch * (HBINS / 256);
            int bend = b + (HBINS / 256) - 1;
            while (b < bend && cum + (long long)hh[b] <= target) { cum += hh[b]; ++b; }
            unsigned cnt = hh[b] ? hh[b] : 1u;
            double lo = (double)b / (double)HSCALE;
            vq[s] = lo + (1.0 / (double)HSCALE) * (((double)(target - cum) + 0.5) / (double)cnt);
        }
        double qq = vq[0] + frac * (vq[1] - vq[0]);
        shb[0] = (double)(float)qq;

        int ns = (int)wsu[WS_SPCNT]; if (ns > SPCAP) ns = SPCAP;
        int nc = 0;
        for (int e = 0; e < ns; ++e) {
            int rr_ = (int)wsu[WS_SPDATA + 3 * e];
            int cc_ = (int)wsu[WS_SPDATA + 3 * e + 1];
            float cv = wsf[WS_SPDATA + 3 * e + 2];
            sp_r[e] = rr_;
            sp_k[e] = fmaxf(expf(-cv / 0.05f), 1e-8f);
            int f = -1;
            for (int x = 0; x < nc; ++x) if (colid[x] == cc_) { f = x; break; }
            if (f < 0) { f = nc; colid[nc] = cc_; ++nc; }
            colof[e] = f;
        }
        sh_ni[0] = ns; sh_ni[1] = nc;
    }
    __syncthreads();

    const double q = shb[0];
    const float qf = (float)q;
    const int ns = sh_ni[0];
    const int nc = sh_ni[1];
    const double Kv   = (double)1e-8f;
    const double EPSd = (double)1e-8f;
    const double kd   = (double)fmaxf(expf(-qf / 0.05f), 1e-8f);
    const double tmm  = (double)(float)(1.0 / 131072.0);
    const double sm_k = (double)(float)(0.95 / 256.0);
    const double sm_d = (double)0.05f;

    for (int x = t; x < nc; x += 256) vov[x] = 1.0;
    if (t == 0) shb[3] = 1.0;
    __syncthreads();

    for (int iter = 0; iter < 30; ++iter) {
        if (t == 0) {
            double vb = shb[3];
            double SV = (double)NN * vb;
            for (int x = 0; x < nc; ++x) SV += vov[x] - vb;
            shb[1] = SV;
        }
        __syncthreads();
        double SV = shb[1];
        double corr = 0.0;
        for (int e = 0; e < ns; ++e)
            if (sp_r[e] == t) corr += ((double)sp_k[e] - Kv) * vov[colof[e]];
        double ut = pow(sm_k / fmax(Kv * SV + corr, EPSd), 0.95);
        sh_u[t] = ut;
        if (t == 0) sh_u[256] = pow(sm_d / fmax(kd * SV, EPSd), 0.95);
        // parallel Suk
        double v = ut;
        v += __shfl_xor(v, 1);  v += __shfl_xor(v, 2);  v += __shfl_xor(v, 4);
        v += __shfl_xor(v, 8);  v += __shfl_xor(v, 16); v += __shfl_xor(v, 32);
        if ((t & 63) == 0) shred[wid] = v;
        __syncthreads();
        if (t == 0) {
            double Suk = shred[0] + shred[1] + shred[2] + shred[3];
            double ktub = Kv * Suk + kd * sh_u[256];
            shb[2] = ktub;
            shb[4] = Suk;
            shb[3] = pow(tmm / fmax(ktub, EPSd), 0.95);
        }
        __syncthreads();
        if (t < nc) {
            double cc = 0.0;
            for (int e = 0; e < ns; ++e)
                if (colof[e] == t) cc += ((double)sp_k[e] - Kv) * sh_u[sp_r[e]];
            vov[t] = pow(tmm / fmax(shb[2] + cc, EPSd), 0.95);
        }
        __syncthreads();
    }

    const double vb = shb[3];
    const double Suk = shb[4];
    const double u_d = sh_u[256];
    const double den = fmax(Kv * vb * Suk, EPSd);
    {
        double pv = sh_u[t] * Kv * vb;
        wsf[WS_PROW + t] = (float)pv;
        float c = (float)(pv / den);
        csf[t] = c;
        wsf[WS_CS + t] = c;
    }
    // parallel SR = sum(u_i * rowsum_i)
    {
        double v = sh_u[t] * (double)rs_t;
        v += __shfl_xor(v, 1);  v += __shfl_xor(v, 2);  v += __shfl_xor(v, 4);
        v += __shfl_xor(v, 8);  v += __shfl_xor(v, 16); v += __shfl_xor(v, 32);
        if ((t & 63) == 0) shred[wid] = v;
    }
    __syncthreads();
    if (t == 0) {
        double SR = shred[0] + shred[1] + shred[2] + shred[3];
        wsf[WS_PROW + 256] = (float)(u_d * kd * vb);
        double SV = (double)NN * vb;
        for (int x = 0; x < nc; ++x) SV += vov[x] - vb;
        float best = csf[0]; int ai = 0;
        for (int i = 1; i < 256; ++i) if (csf[i] > best) { best = csf[i]; ai = i; }
        double cmb = vb * (Kv * Suk + kd * u_d);
        float dscf = (float)((u_d * kd * vb) / fmax(cmb, EPSd));
        float munk = dscf / (dscf + best + 1e-8f);
        double loss = Kv * vb * SR + kd * u_d * q * SV;
        double total = (Kv * Suk + kd * u_d) * SV;
        double dust = u_d * kd * SV;
        for (int e = 0; e < ns; ++e) {
            double extra = ((double)sp_k[e] - Kv) * sh_u[sp_r[e]] * vov[colof[e]];
            loss += extra * (double)wsf[WS_SPDATA + 3 * e + 2];
            total += extra;
        }
        out[LOSS_OFF]  = (float)loss;
        out[DUSTC_OFF] = qf;
        out[RATIO_OFF] = (float)(dust / fmax(total, EPSd));
        wsf[WS_Q]    = qf;
        wsf[WS_DSC]  = dscf;
        wsf[WS_BKM]  = best;
        wsf[WS_MUNK] = munk;
        wsf[WS_AVAL] = (float)ai;
    }
}

// ---------------- K3: bulk output fills ----------------
__global__ __launch_bounds__(256) void k_fill(const float* __restrict__ wsf,
                                              float* __restrict__ out)
{
    __shared__ float csL[256];
    const int t = threadIdx.x;
    csL[t] = wsf[WS_CS + t];
    __syncthreads();
    const int r = blockIdx.x >> 7;
    const int seg = blockIdx.x & 127;
    const size_t segoff = (size_t)seg * 1024;
    if (r == 0) {
        float v = wsf[WS_Q];
        float4 v4 = make_float4(v, v, v, v);
        *(float4*)(out + CEXT_DUST + segoff + t * 4) = v4;
    } else if (r < 258) {
        int i = r - 1;
        float v = wsf[WS_PROW + i];
        float4 v4 = make_float4(v, v, v, v);
        *(float4*)(out + PLAN_OFF + (size_t)i * NN + segoff + t * 4) = v4;
    } else if (r < 514) {
        int c = r - 258;   // CS_OFF misaligned by 3 floats -> keep coalesced dwords
        float v = csL[t];
        size_t base = CS_OFF + (size_t)c * NN + segoff;
#pragma unroll
        for (int k = 0; k < 4; ++k) out[base + k * 256 + t] = v;
    } else if (r == 514) {
        float q = wsf[WS_Q];
#pragma unroll
        for (int k = 0; k < 4; ++k) {
            size_t j = segoff + k * 256 + t;
            float md = out[MD_OFF + j];
            out[DUS_OFF + j] = 1.0f / (1.0f + expf(-(md - q) / 0.05f));
        }
    } else {
        int rr = r - 515;
        float v = (rr == 0) ? wsf[WS_DSC] : (rr == 1) ? wsf[WS_BKM]
                : (rr == 2) ? wsf[WS_MUNK] : wsf[WS_AVAL];
        size_t base = ((rr == 0) ? DSC_OFF : (rr == 1) ? BKM_OFF
                     : (rr == 2) ? MUNK_OFF : ASSIGN_OFF) + segoff;
#pragma unroll
        for (int k = 0; k < 4; ++k) out[base + k * 256 + t] = v;
    }
}

extern "C" void kernel_launch(void* const* d_in, const int* in_sizes, int n_in,
                              void* d_out, int out_size, void* d_ws, size_t ws_size,
                              hipStream_t stream)
{
    const float* A = (const float*)d_in[0];   // source_proto [256,256]
    const float* B = (const float*)d_in[1];   // target_feat [131072,256]
    float* out = (float*)d_out;
    float* wsf = (float*)d_ws;
    unsigned* wsu = (unsigned*)d_ws;

    k_init<<<320, 256, 0, stream>>>(A, wsf, wsu);
    k_cost<<<2048, 256, 0, stream>>>(B, out, wsu, wsf);
    k_solve<<<1, 256, 0, stream>>>(wsu, wsf, out);
    k_fill<<<519 * 128, 256, 0, stream>>>(wsf, out);
}